// Round 14
// baseline (354.845 us; speedup 1.0000x reference)
//
#include <hip/hip_runtime.h>
#include <hip/hip_bf16.h>
#include <math.h>

#define NB 4
#define NN 128
#define NF 128
#define NS 5
#define NT 32
#define NL 2

typedef __hip_bfloat16 bf16;
typedef short bf16x8 __attribute__((ext_vector_type(8)));
typedef float f32x4 __attribute__((ext_vector_type(4)));

__device__ __forceinline__ float b2f(const bf16 x) { return __bfloat162float(x); }
__device__ __forceinline__ float fast_rcp(float x) { return __builtin_amdgcn_rcpf(x); }
__device__ __forceinline__ float fast_rsq(float x) { return __builtin_amdgcn_rsqf(x); }
__device__ __forceinline__ float silu_fast(float x) { return x * fast_rcp(1.0f + __expf(-x)); }
__device__ __forceinline__ float ldf(const void* p, int i, int fl) {
  return fl ? b2f(((const bf16*)p)[i]) : ((const float*)p)[i];
}
// float -> bf16 bits (RNE)
__device__ __forceinline__ short f2bf(float x) {
  unsigned u = __float_as_uint(x);
  unsigned r = (u + 0x7fffu + ((u >> 16) & 1u)) >> 16;
  return (short)r;
}

#define PI_F 3.14159265358979323846f
#define SQRT3_F 1.7320508075688772f

// converted-weights region offsets (floats) within d_ws after the flag slot
#define POS_OFF 0
#define GF_OFF  1536
#define WE_OFF  1664
#define BE_OFF  6400
#define WR1_OFF 6528
#define BR1_OFF 6656
#define WR2_OFF 6784
#define WN_OFF  72320
#define C1_OFF  105088
#define C2_OFF  106112
#define C3_OFF  107136
#define M0_OFF  108160
#define M1_OFF  140928
#define G1_OFF  173696
#define G2_OFF  177792
#define WV_OFF  181888
#define CVT_TOTAL 182144

// ---------------------------------------------------------------------------
// prep_convert: detect dtype, convert cvt region, prep rows: env, z layer-0,
// Ag=0, posA, counters=0. (vec is no longer pre-zeroed: layer 0 skips it.)
// ---------------------------------------------------------------------------
__global__ void prep_convert_kernel(
    const void* __restrict__ pos_raw, const int* __restrict__ nfeat,
    const void* __restrict__ gf,  const void* __restrict__ we,
    const void* __restrict__ be,  const void* __restrict__ wr1,
    const void* __restrict__ br1, const void* __restrict__ wr2,
    const void* __restrict__ wn,  const void* __restrict__ c1,
    const void* __restrict__ c2,  const void* __restrict__ c3,
    const void* __restrict__ m0,  const void* __restrict__ m1,
    const void* __restrict__ g1,  const void* __restrict__ g2,
    const void* __restrict__ wv,
    int* __restrict__ flag, float* __restrict__ cvt,
    float* __restrict__ posA, float* __restrict__ z,
    float* __restrict__ env, float* __restrict__ Ag,
    int* __restrict__ cnt)
{
  __shared__ float posB[NN*3];
  __shared__ float scs[NF];
  __shared__ int sbad;
  const int tid = threadIdx.x;
  const int bn  = blockIdx.x;        // node row, 0..511
  const int b   = bn >> 7;
  const int n   = bn & 127;

  if (tid == 0) sbad = 0;
  __syncthreads();
  {
    const bf16* p = (const bf16*)pos_raw;
    int bad = 0;
    for (int i = tid; i < NB*NN*3; i += 256) {
      float v = b2f(p[i]);
      if (!(fabsf(v) <= 1024.0f)) bad = 1;   // NaN also fails
    }
    if (bad) sbad = 1;
  }
  __syncthreads();
  const int fl = sbad ? 0 : 1;               // 1 = bf16 inputs
  if (bn == 0 && tid == 0) *flag = fl;
  if (bn == 0 && tid < NB*32) cnt[tid] = 0;  // per-(b,rt) arrival counters

  for (int i = bn*256 + tid; i < CVT_TOTAL; i += 512*256) {
    const void* src; int j;
    if      (i < GF_OFF)  { src = pos_raw; j = i - POS_OFF; }
    else if (i < WE_OFF)  { src = gf;  j = i - GF_OFF; }
    else if (i < BE_OFF)  { src = we;  j = i - WE_OFF; }
    else if (i < WR1_OFF) { src = be;  j = i - BE_OFF; }
    else if (i < BR1_OFF) { src = wr1; j = i - WR1_OFF; }
    else if (i < WR2_OFF) { src = br1; j = i - BR1_OFF; }
    else if (i < WN_OFF)  { src = wr2; j = i - WR2_OFF; }
    else if (i < C1_OFF)  { src = wn;  j = i - WN_OFF; }
    else if (i < C2_OFF)  { src = c1;  j = i - C1_OFF; }
    else if (i < C3_OFF)  { src = c2;  j = i - C2_OFF; }
    else if (i < M0_OFF)  { src = c3;  j = i - C3_OFF; }
    else if (i < M1_OFF)  { src = m0;  j = i - M0_OFF; }
    else if (i < G1_OFF)  { src = m1;  j = i - M1_OFF; }
    else if (i < G2_OFF)  { src = g1;  j = i - G1_OFF; }
    else if (i < WV_OFF)  { src = g2;  j = i - G2_OFF; }
    else                  { src = wv;  j = i - WV_OFF; }
    cvt[i] = fl ? b2f(((const bf16*)src)[j]) : ((const float*)src)[j];
  }

  for (int i = tid; i < NN*3; i += 256)
    posB[i] = ldf(pos_raw, b*NN*3 + i, fl);
  if (tid < 128) {
    int sp = nfeat[bn] - 1;
    float acc = ldf(we, sp*NF + tid, fl) + ldf(be, tid, fl);
    #pragma unroll 8
    for (int t = 0; t < NT; ++t)
      acc += ldf(gf, b*NT + t, fl) * ldf(we, (NS + t)*NF + tid, fl);
    scs[tid] = acc;
  }
  __syncthreads();

  if (tid < 128) {
    const int f = tid;
    {
      float px = posB[n*3+0], py = posB[n*3+1], pz = posB[n*3+2];
      float vx = px - posB[f*3+0];
      float vy = py - posB[f*3+1];
      float vz = pz - posB[f*3+2];
      float lng = sqrtf(vx*vx + vy*vy + vz*vz + 1e-12f);
      env[bn*NN + f] = (lng < 10.0f) ? 0.5f*(cosf(PI_F*lng*0.1f) + 1.0f) : 0.0f;
    }
    {
      float acc = 0.f;
      if (fl) {
        const bf16* W = (const bf16*)wn;
        #pragma unroll 8
        for (int k = 0; k < NF; ++k) acc += scs[k] * b2f(W[k*NF + f]);
      } else {
        const float* W = (const float*)wn;
        #pragma unroll 8
        for (int k = 0; k < NF; ++k) acc += scs[k] * W[k*NF + f];
      }
      z[bn*NF + f] = acc;
    }
    float* Arow = Ag + (size_t)bn*4*NF;
    #pragma unroll
    for (int c = 0; c < 4; ++c) Arow[c*NF + f] = 0.f;
    if (f < 3) posA[bn*3 + f] = posB[n*3 + f];
  }
}

// ---------------------------------------------------------------------------
// LAYER v10 = EDGE v9 (MFMA + VGPR accum + pipeline, 1024 blocks, 4/CU) with
// the NODE phase fused via last-block-per-(b,rt): after the Ag atomics, the
// 8th-arriving sender-group block (device-scope counter) runs gate + mix
// GEMMs + gate MLP + pos update for its 4 receivers, re-zeros Ag + counter.
// Layer 0 skips vec loads (vec == 0 identically).
// ---------------------------------------------------------------------------
__global__ __launch_bounds__(256, 2)
void layer_kernel(const float* __restrict__ pos_in,
                  const float* __restrict__ z_in,
                  const float* __restrict__ vec_in,
                  const float* __restrict__ env,
                  const float* __restrict__ cvt,
                  int layer, int last,
                  float* __restrict__ pos_out,
                  float* __restrict__ z_out,
                  float* __restrict__ vec_out,
                  float* __restrict__ Ag, int* __restrict__ cnt,
                  const int* __restrict__ flag, void* __restrict__ out)
{
  __shared__ float posL[NN*3];                     // 1.5 KB
  __shared__ float envL[4][16];
  __shared__ float w1L[64], b1L[64];
  __shared__ __align__(16) short hidA[2][16][72];  // 4.5 KB bf16 A tiles
  __shared__ __align__(16) float4 zvp[2][4][NF];   // 16 KB
  __shared__ __align__(16) float4 uenvL[2][4][4];  // [buf][r][si]
  // node-phase LDS (used only by the last block)
  __shared__ float AshN[2][4][NF];                 // 4 KB
  __shared__ float scsN[2][NF];
  __shared__ float h16N[2][16];
  __shared__ float redN[4][3];
  __shared__ int sLast;

  const int tid  = threadIdx.x;
  const int bidx = blockIdx.x;                   // b*256 + rt*8 + sg
  const int b    = bidx >> 8;
  const int rt   = (bidx >> 3) & 31;
  const int sg   = bidx & 7;
  const int r0   = rt * 4;
  const int sbase= sg * 16;

  const int wvid  = tid >> 6;                    // wave id 0..3
  const int lane  = tid & 63;
  const int n16   = lane & 15;                   // MFMA n / A-row index
  const int q     = lane >> 4;                   // quarter -> receiver
  const int halfB = wvid >> 1;                   // 0: ell0 cols, 1: ell1 cols

  // ---- prologue ----
  for (int i = tid; i < NN*3; i += 256)
    posL[i] = pos_in[b*NN*3 + i];
  if (tid < 64) {
    int rr = tid >> 4, j = tid & 15;
    envL[rr][j] = env[(b*NN + r0 + rr)*NN + sbase + j];
    w1L[tid] = cvt[WR1_OFF + layer*64 + tid];
    b1L[tid] = cvt[BR1_OFF + layer*64 + tid];
  }
  bf16x8 bfr[4][2];
  {
    const float* W2 = cvt + WR2_OFF + layer*64*512;
    #pragma unroll
    for (int t = 0; t < 4; ++t) {
      int col = wvid*64 + t*16 + n16;            // 0..255
      #pragma unroll
      for (int ks = 0; ks < 2; ++ks) {
        #pragma unroll
        for (int j = 0; j < 8; ++j) {
          int k = ks*32 + q*8 + j;
          float v = W2[k*512 + col];
          if (halfB) v *= SQRT3_F;
          bfr[t][ks][j] = f2bf(v);
        }
      }
    }
  }
  float acR[12];
  #pragma unroll
  for (int i = 0; i < 12; ++i) acR[i] = 0.f;

  __syncthreads();   // posL/envL/w1L ready

  const int rme = wvid;                          // receiver staged by this wave
  const float hrx = posL[(r0 + rme)*3 + 0];
  const float hry = posL[(r0 + rme)*3 + 1];
  const float hrz = posL[(r0 + rme)*3 + 2];
  const float w1v = w1L[lane], b1v = b1L[lane];

  const int fS  = tid & 127;                     // staging column
  const int si0 = tid >> 7;                      // staging sender base (0/1)

  float4 pv[2];                                  // prefetch registers

  // ---- stage chunk 0 ----
  #pragma unroll
  for (int rep = 0; rep < 2; ++rep) {
    int gs = b*NN + sbase + 0 + si0 + 2*rep;
    pv[rep].x = z_in[gs*NF + fS];
    if (layer == 0) {
      pv[rep].y = 0.f; pv[rep].z = 0.f; pv[rep].w = 0.f;
    } else {
      pv[rep].y = vec_in[((size_t)gs*3 + 0)*NF + fS];
      pv[rep].z = vec_in[((size_t)gs*3 + 1)*NF + fS];
      pv[rep].w = vec_in[((size_t)gs*3 + 2)*NF + fS];
    }
  }
  #pragma unroll
  for (int si = 0; si < 4; ++si) {
    int s = sbase + si;
    float vx = hrx - posL[s*3 + 0];
    float vy = hry - posL[s*3 + 1];
    float vz = hrz - posL[s*3 + 2];
    float d = vx*vx + vy*vy + vz*vz + 1e-12f;
    float lng = d * fast_rsq(d);
    hidA[0][rme*4 + si][lane] = f2bf(silu_fast(lng * w1v + b1v));
  }
  if (tid < 16) {
    int r = tid >> 2, si = tid & 3;
    int s = sbase + si;
    float vx = posL[(r0 + r)*3 + 0] - posL[s*3 + 0];
    float vy = posL[(r0 + r)*3 + 1] - posL[s*3 + 1];
    float vz = posL[(r0 + r)*3 + 2] - posL[s*3 + 2];
    float d = vx*vx + vy*vy + vz*vz + 1e-12f;
    float inv = fast_rsq(d);
    float envw = (s == r0 + r) ? 0.f : envL[r][si] * 0.0625f;
    uenvL[0][r][si] = make_float4(vx*inv, vy*inv, vz*inv, envw);
  }
  #pragma unroll
  for (int rep = 0; rep < 2; ++rep)
    zvp[0][si0 + 2*rep][fS] = pv[rep];
  __syncthreads();

  // ---- pipelined chunk loop: 1 barrier per chunk ----
  #pragma unroll
  for (int c = 0; c < 4; ++c) {
    const int cb = c & 1, nb = cb ^ 1;
    const int nc0 = (c + 1) * 4;

    if (c < 3) {
      #pragma unroll
      for (int rep = 0; rep < 2; ++rep) {
        int gs = b*NN + sbase + nc0 + si0 + 2*rep;
        pv[rep].x = z_in[gs*NF + fS];
        if (layer == 0) {
          pv[rep].y = 0.f; pv[rep].z = 0.f; pv[rep].w = 0.f;
        } else {
          pv[rep].y = vec_in[((size_t)gs*3 + 0)*NF + fS];
          pv[rep].z = vec_in[((size_t)gs*3 + 1)*NF + fS];
          pv[rep].w = vec_in[((size_t)gs*3 + 2)*NF + fS];
        }
      }
    }

    // ---- MFMA radial GEMM + consume (buffer cb) ----
    bf16x8 af0 = *(const bf16x8*)&hidA[cb][n16][q*8];
    bf16x8 af1 = *(const bf16x8*)&hidA[cb][n16][q*8 + 32];
    float4 ue[4];
    #pragma unroll
    for (int si = 0; si < 4; ++si) ue[si] = uenvL[cb][q][si];

    #pragma unroll
    for (int t = 0; t < 4; ++t) {
      f32x4 Cf = {0.f, 0.f, 0.f, 0.f};
      Cf = __builtin_amdgcn_mfma_f32_16x16x32_bf16(af0, bfr[t][0], Cf, 0, 0, 0);
      Cf = __builtin_amdgcn_mfma_f32_16x16x32_bf16(af1, bfr[t][1], Cf, 0, 0, 0);
      int f = (wvid*64 + t*16 + n16) & 127;      // feature index
      if (!halfB) {
        float a0 = 0.f;
        #pragma unroll
        for (int si = 0; si < 4; ++si) {
          float4 zv = zvp[cb][si][f];
          float fv = zv.x + ue[si].x*zv.y + ue[si].y*zv.z + ue[si].z*zv.w;
          a0 += (Cf[si] * ue[si].w) * fv;        // C row = q*4+si -> edge(q,si)
        }
        acR[t] += a0;
      } else {
        float t1 = 0.f, t2 = 0.f, t3 = 0.f;
        #pragma unroll
        for (int si = 0; si < 4; ++si) {
          float4 zv = zvp[cb][si][f];
          float fv = zv.x + ue[si].x*zv.y + ue[si].y*zv.z + ue[si].z*zv.w;
          float tt = (Cf[si] * ue[si].w) * fv;   // sqrt3 folded into B
          t1 += tt * ue[si].x;
          t2 += tt * ue[si].y;
          t3 += tt * ue[si].z;
        }
        acR[t*3 + 0] += t1;
        acR[t*3 + 1] += t2;
        acR[t*3 + 2] += t3;
      }
    }

    // ---- stage next chunk into buffer nb ----
    if (c < 3) {
      #pragma unroll
      for (int si = 0; si < 4; ++si) {
        int s = sbase + nc0 + si;
        float vx = hrx - posL[s*3 + 0];
        float vy = hry - posL[s*3 + 1];
        float vz = hrz - posL[s*3 + 2];
        float d = vx*vx + vy*vy + vz*vz + 1e-12f;
        float lng = d * fast_rsq(d);
        hidA[nb][rme*4 + si][lane] = f2bf(silu_fast(lng * w1v + b1v));
      }
      if (tid < 16) {
        int r = tid >> 2, si = tid & 3;
        int s = sbase + nc0 + si;
        float vx = posL[(r0 + r)*3 + 0] - posL[s*3 + 0];
        float vy = posL[(r0 + r)*3 + 1] - posL[s*3 + 1];
        float vz = posL[(r0 + r)*3 + 2] - posL[s*3 + 2];
        float d = vx*vx + vy*vy + vz*vz + 1e-12f;
        float inv = fast_rsq(d);
        float envw = (s == r0 + r) ? 0.f : envL[r][nc0 + si] * 0.0625f;
        uenvL[nb][r][si] = make_float4(vx*inv, vy*inv, vz*inv, envw);
      }
      #pragma unroll
      for (int rep = 0; rep < 2; ++rep)
        zvp[nb][si0 + 2*rep][fS] = pv[rep];
    }
    __syncthreads();
  }

  // ---- edge epilogue: coalesced atomics straight from VGPRs ----
  const size_t rowbase = (size_t)(b*NN + r0 + q)*4;   // receiver q
  if (!halfB) {
    #pragma unroll
    for (int t = 0; t < 4; ++t) {
      int f = (wvid*64 + t*16 + n16) & 127;
      atomicAdd(Ag + (rowbase + 0)*NF + f, acR[t]);
    }
  } else {
    #pragma unroll
    for (int t = 0; t < 4; ++t) {
      int f = (wvid*64 + t*16 + n16) & 127;
      atomicAdd(Ag + (rowbase + 1)*NF + f, acR[t*3 + 0]);
      atomicAdd(Ag + (rowbase + 2)*NF + f, acR[t*3 + 1]);
      atomicAdd(Ag + (rowbase + 3)*NF + f, acR[t*3 + 2]);
    }
  }

  // ---- last-block detection (device-scope counter per (b,rt)) ----
  __threadfence();           // release: Ag atomics visible before counter bump
  __syncthreads();
  if (tid == 0) {
    int old = atomicAdd(&cnt[b*32 + rt], 1);
    sLast = (old == 7) ? 1 : 0;
  }
  __syncthreads();
  if (!sLast) return;
  __threadfence();           // acquire: other blocks' Ag atomics visible

  // =================== fused NODE phase (last block only) ==================
  const int rowh = tid >> 7;                     // 0/1
  const int f    = tid & 127;

  for (int hf = 0; hf < 2; ++hf) {
    const int row = r0 + hf*2 + rowh;
    const int bn  = b*NN + row;

    // load raw A, re-zero for next layer, apply correlation gate
    {
      float* Arow = Ag + (size_t)bn*4*NF;
      float a0 = Arow[0*NF + f];
      float a1 = Arow[1*NF + f];
      float a2 = Arow[2*NF + f];
      float a3 = Arow[3*NF + f];
      Arow[0*NF + f] = 0.f;
      Arow[1*NF + f] = 0.f;
      Arow[2*NF + f] = 0.f;
      Arow[3*NF + f] = 0.f;
      float n0 = a0*a0;
      float C1 = cvt[C1_OFF + (layer*4 + 0)*NF + f];
      float C2 = cvt[C2_OFF + (layer*4 + 0)*NF + f];
      float C3 = cvt[C3_OFF + (layer*4 + 0)*NF + f];
      float g0 = 1.0f + C1*n0 + C2*n0*n0 + C3*n0*n0*n0;
      float n1 = a1*a1 + a2*a2 + a3*a3;
      float D1 = cvt[C1_OFF + (layer*4 + 1)*NF + f];
      float D2 = cvt[C1_OFF + (layer*4 + 1)*NF + f - C1_OFF + C2_OFF];  // C2 slot
      float D3 = cvt[C3_OFF + (layer*4 + 1)*NF + f];
      D2 = cvt[C2_OFF + (layer*4 + 1)*NF + f];
      float g1 = 1.0f + D1*n1 + D2*n1*n1 + D3*n1*n1*n1;
      AshN[rowh][0][f] = a0 * g0;
      AshN[rowh][1][f] = a1 * g1;
      AshN[rowh][2][f] = a2 * g1;
      AshN[rowh][3][f] = a3 * g1;
    }
    __syncthreads();

    const float* M0 = cvt + M0_OFF + layer*NF*NF;
    const float* M1 = cvt + M1_OFF + layer*NF*NF;
    float sn = 0.f, v0 = 0.f, v1 = 0.f, v2 = 0.f;
    #pragma unroll 4
    for (int k = 0; k < NF; ++k) {
      float m0 = M0[k*NF + f];
      float m1 = M1[k*NF + f];
      sn += AshN[rowh][0][k] * m0;
      v0 += AshN[rowh][1][k] * m1;
      v1 += AshN[rowh][2][k] * m1;
      v2 += AshN[rowh][3][k] * m1;
    }
    scsN[rowh][f] = sn;
    __syncthreads();

    if (!last) {
      const float* W = cvt + WN_OFF + (layer+1)*NF*NF;
      float acc = 0.f;
      #pragma unroll 8
      for (int k = 0; k < NF; ++k)
        acc += scsN[rowh][k] * W[k*NF + f];
      z_out[bn*NF + f] = acc;
    }
    if (f < 16) {
      const float* G1 = cvt + G1_OFF + layer*NF*16;
      float acc = 0.f;
      #pragma unroll 8
      for (int k = 0; k < NF; ++k)
        acc += scsN[rowh][k] * G1[k*16 + f];
      h16N[rowh][f] = silu_fast(acc);
    }
    __syncthreads();

    {
      const float* G2 = cvt + G2_OFF + layer*16*NF;
      float gate = 0.f;
      #pragma unroll
      for (int j = 0; j < 16; ++j)
        gate += h16N[rowh][j] * G2[j*NF + f];
      float gv = gate * cvt[WV_OFF + layer*NF + f];

      if (!last) {
        vec_out[((size_t)bn*3 + 0)*NF + f] = v0;
        vec_out[((size_t)bn*3 + 1)*NF + f] = v1;
        vec_out[((size_t)bn*3 + 2)*NF + f] = v2;
      }

      float p0 = v0*gv, p1 = v1*gv, p2 = v2*gv;
      #pragma unroll
      for (int off = 32; off > 0; off >>= 1) {
        p0 += __shfl_down(p0, off, 64);
        p1 += __shfl_down(p1, off, 64);
        p2 += __shfl_down(p2, off, 64);
      }
      if (lane == 0) { redN[wvid][0] = p0; redN[wvid][1] = p1; redN[wvid][2] = p2; }
    }
    __syncthreads();

    if (f == 0) {                                // tid 0 (rowh 0), tid 128 (rowh 1)
      float m0 = redN[rowh*2][0] + redN[rowh*2+1][0];
      float m1 = redN[rowh*2][1] + redN[rowh*2+1][1];
      float m2 = redN[rowh*2][2] + redN[rowh*2+1][2];
      float px = posL[row*3+0] + m0;
      float py = posL[row*3+1] + m1;
      float pz = posL[row*3+2] + m2;
      if (!last) {
        pos_out[bn*3+0] = px;
        pos_out[bn*3+1] = py;
        pos_out[bn*3+2] = pz;
      } else {
        float ox = px - cvt[POS_OFF + bn*3+0];
        float oy = py - cvt[POS_OFF + bn*3+1];
        float oz = pz - cvt[POS_OFF + bn*3+2];
        if (*flag) {
          bf16* o = (bf16*)out;
          o[bn*3+0] = __float2bfloat16(ox);
          o[bn*3+1] = __float2bfloat16(oy);
          o[bn*3+2] = __float2bfloat16(oz);
        } else {
          float* o = (float*)out;
          o[bn*3+0] = ox;
          o[bn*3+1] = oy;
          o[bn*3+2] = oz;
        }
      }
    }
    __syncthreads();                             // protect LDS before next half
  }

  if (tid == 0) cnt[b*32 + rt] = 0;              // reset counter for next layer
}

// ---------------------------------------------------------------------------
extern "C" void kernel_launch(void* const* d_in, const int* in_sizes, int n_in,
                              void* d_out, int out_size, void* d_ws, size_t ws_size,
                              hipStream_t stream)
{
  (void)in_sizes; (void)n_in; (void)out_size; (void)ws_size;
  const int* nfeat = (const int*)d_in[1];

  float* ws   = (float*)d_ws;
  int*   flag = (int*)ws;                       // 16 floats reserved
  float* cvt  = ws + 16;                        // CVT_TOTAL floats
  float* posA = cvt + CVT_TOTAL;                // 1536
  float* posB = posA + NB*NN*3;                 // 1536
  float* zA   = posB + NB*NN*3;                 // 65536
  float* zB   = zA + NB*NN*NF;                  // 65536
  float* vecB = zB + NB*NN*NF;                  // 196608 (layer0 -> layer1)
  float* Ag   = vecB + NB*NN*3*NF;              // 262144
  float* env  = Ag + NB*NN*4*NF;                // 65536
  int*   cnt  = (int*)(env + NB*NN*NN);         // 128 ints

  prep_convert_kernel<<<512, 256, 0, stream>>>(
      d_in[0], nfeat, d_in[2], d_in[3], d_in[4], d_in[5], d_in[6], d_in[7],
      d_in[8], d_in[9], d_in[10], d_in[11], d_in[12], d_in[13], d_in[14],
      d_in[15], d_in[16], flag, cvt, posA, zA, env, Ag, cnt);

  layer_kernel<<<1024, 256, 0, stream>>>(
      posA, zA, /*vec_in (unused, layer0)*/ zA, env, cvt, 0, 0,
      posB, zB, vecB, Ag, cnt, flag, d_out);
  layer_kernel<<<1024, 256, 0, stream>>>(
      posB, zB, vecB, env, cvt, 1, 1,
      posA, zA, vecB, Ag, cnt, flag, d_out);
}

// Round 16
// 181.684 us; speedup vs baseline: 1.9531x; 1.9531x over previous
//
#include <hip/hip_runtime.h>
#include <hip/hip_bf16.h>
#include <math.h>

#define NB 4
#define NN 128
#define NF 128
#define NS 5
#define NT 32
#define NL 2

typedef __hip_bfloat16 bf16;
typedef short bf16x8 __attribute__((ext_vector_type(8)));
typedef float f32x4 __attribute__((ext_vector_type(4)));

__device__ __forceinline__ float b2f(const bf16 x) { return __bfloat162float(x); }
__device__ __forceinline__ float fast_rcp(float x) { return __builtin_amdgcn_rcpf(x); }
__device__ __forceinline__ float fast_rsq(float x) { return __builtin_amdgcn_rsqf(x); }
__device__ __forceinline__ float silu_fast(float x) { return x * fast_rcp(1.0f + __expf(-x)); }
__device__ __forceinline__ float ldf(const void* p, int i, int fl) {
  return fl ? b2f(((const bf16*)p)[i]) : ((const float*)p)[i];
}
// float -> bf16 bits (RNE)
__device__ __forceinline__ short f2bf(float x) {
  unsigned u = __float_as_uint(x);
  unsigned r = (u + 0x7fffu + ((u >> 16) & 1u)) >> 16;
  return (short)r;
}

#define PI_F 3.14159265358979323846f
#define SQRT3_F 1.7320508075688772f

// converted-weights region offsets (floats) within d_ws after the flag slot
#define POS_OFF 0
#define GF_OFF  1536
#define WE_OFF  1664
#define BE_OFF  6400
#define WR1_OFF 6528
#define BR1_OFF 6656
#define WR2_OFF 6784
#define WN_OFF  72320
#define C1_OFF  105088
#define C2_OFF  106112
#define C3_OFF  107136
#define M0_OFF  108160
#define M1_OFF  140928
#define G1_OFF  173696
#define G2_OFF  177792
#define WV_OFF  181888
#define CVT_TOTAL 182144

#define AG_SLICE ((size_t)NB*NN*4*NF)          // floats per sender-group slice

// ---------------------------------------------------------------------------
// prep_convert: detect dtype, convert cvt region, prep node rows: env row,
// z layer-0, pos_cur. (No Ag zeroing: edge writes every Agp element; no vec
// zeroing: layer-0 edge skips vec.)
// ---------------------------------------------------------------------------
__global__ void prep_convert_kernel(
    const void* __restrict__ pos_raw, const int* __restrict__ nfeat,
    const void* __restrict__ gf,  const void* __restrict__ we,
    const void* __restrict__ be,  const void* __restrict__ wr1,
    const void* __restrict__ br1, const void* __restrict__ wr2,
    const void* __restrict__ wn,  const void* __restrict__ c1,
    const void* __restrict__ c2,  const void* __restrict__ c3,
    const void* __restrict__ m0,  const void* __restrict__ m1,
    const void* __restrict__ g1,  const void* __restrict__ g2,
    const void* __restrict__ wv,
    int* __restrict__ flag, float* __restrict__ cvt,
    float* __restrict__ pos_cur, float* __restrict__ z,
    float* __restrict__ env)
{
  __shared__ float posB[NN*3];
  __shared__ float scs[NF];
  __shared__ int sbad;
  const int tid = threadIdx.x;
  const int bn  = blockIdx.x;        // node row, 0..511
  const int b   = bn >> 7;
  const int n   = bn & 127;

  if (tid == 0) sbad = 0;
  __syncthreads();
  {
    const bf16* p = (const bf16*)pos_raw;
    int bad = 0;
    for (int i = tid; i < NB*NN*3; i += 256) {
      float v = b2f(p[i]);
      if (!(fabsf(v) <= 1024.0f)) bad = 1;   // NaN also fails
    }
    if (bad) sbad = 1;
  }
  __syncthreads();
  const int fl = sbad ? 0 : 1;               // 1 = bf16 inputs
  if (bn == 0 && tid == 0) *flag = fl;

  for (int i = bn*256 + tid; i < CVT_TOTAL; i += 512*256) {
    const void* src; int j;
    if      (i < GF_OFF)  { src = pos_raw; j = i - POS_OFF; }
    else if (i < WE_OFF)  { src = gf;  j = i - GF_OFF; }
    else if (i < BE_OFF)  { src = we;  j = i - WE_OFF; }
    else if (i < WR1_OFF) { src = be;  j = i - BE_OFF; }
    else if (i < BR1_OFF) { src = wr1; j = i - WR1_OFF; }
    else if (i < WR2_OFF) { src = br1; j = i - BR1_OFF; }
    else if (i < WN_OFF)  { src = wr2; j = i - WR2_OFF; }
    else if (i < C1_OFF)  { src = wn;  j = i - WN_OFF; }
    else if (i < C2_OFF)  { src = c1;  j = i - C1_OFF; }
    else if (i < C3_OFF)  { src = c2;  j = i - C2_OFF; }
    else if (i < M0_OFF)  { src = c3;  j = i - C3_OFF; }
    else if (i < M1_OFF)  { src = m0;  j = i - M0_OFF; }
    else if (i < G1_OFF)  { src = m1;  j = i - M1_OFF; }
    else if (i < G2_OFF)  { src = g1;  j = i - G1_OFF; }
    else if (i < WV_OFF)  { src = g2;  j = i - G2_OFF; }
    else                  { src = wv;  j = i - WV_OFF; }
    cvt[i] = fl ? b2f(((const bf16*)src)[j]) : ((const float*)src)[j];
  }

  for (int i = tid; i < NN*3; i += 256)
    posB[i] = ldf(pos_raw, b*NN*3 + i, fl);
  if (tid < 128) {
    int sp = nfeat[bn] - 1;
    float acc = ldf(we, sp*NF + tid, fl) + ldf(be, tid, fl);
    #pragma unroll 8
    for (int t = 0; t < NT; ++t)
      acc += ldf(gf, b*NT + t, fl) * ldf(we, (NS + t)*NF + tid, fl);
    scs[tid] = acc;
  }
  __syncthreads();

  if (tid < 128) {
    const int f = tid;
    {
      float px = posB[n*3+0], py = posB[n*3+1], pz = posB[n*3+2];
      float vx = px - posB[f*3+0];
      float vy = py - posB[f*3+1];
      float vz = pz - posB[f*3+2];
      float lng = sqrtf(vx*vx + vy*vy + vz*vz + 1e-12f);
      env[bn*NN + f] = (lng < 10.0f) ? 0.5f*(cosf(PI_F*lng*0.1f) + 1.0f) : 0.0f;
    }
    {
      float acc = 0.f;
      if (fl) {
        const bf16* W = (const bf16*)wn;
        #pragma unroll 8
        for (int k = 0; k < NF; ++k) acc += scs[k] * b2f(W[k*NF + f]);
      } else {
        const float* W = (const float*)wn;
        #pragma unroll 8
        for (int k = 0; k < NF; ++k) acc += scs[k] * W[k*NF + f];
      }
      z[bn*NF + f] = acc;
    }
    if (f < 3) pos_cur[bn*3 + f] = posB[n*3 + f];
  }
}

// ---------------------------------------------------------------------------
// EDGE v9c (deterministic): MFMA + VGPR accum + double-buffered pipeline,
// 1024 blocks (4/CU). Epilogue: PLAIN coalesced stores into this sender
// group's private Agp slice (every element written exactly once). No atomics
// -> bit-deterministic across graph replays (round-15 post-timing failure
// was float-atomic ordering flipping a bf16 output ulp).
// ---------------------------------------------------------------------------
__global__ __launch_bounds__(256, 2)
void edge_kernel(const float* __restrict__ pos_cur,
                 const float* __restrict__ z,
                 const float* __restrict__ vec,
                 const float* __restrict__ env,
                 const float* __restrict__ cvt,
                 int layer, float* __restrict__ Agp)
{
  __shared__ float posL[NN*3];                     // 1.5 KB
  __shared__ float envL[4][16];
  __shared__ float w1L[64], b1L[64];
  __shared__ __align__(16) short hidA[2][16][72];  // 4.5 KB bf16 A tiles
  __shared__ __align__(16) float4 zvp[2][4][NF];   // 16 KB
  __shared__ __align__(16) float4 uenvL[2][4][4];  // [buf][r][si]

  const int tid  = threadIdx.x;
  const int bidx = blockIdx.x;                   // b*256 + rt*8 + sg
  const int b    = bidx >> 8;
  const int rt   = (bidx >> 3) & 31;
  const int sg   = bidx & 7;
  const int r0   = rt * 4;
  const int sbase= sg * 16;

  const int wvid  = tid >> 6;                    // wave id 0..3
  const int lane  = tid & 63;
  const int n16   = lane & 15;                   // MFMA n / A-row index
  const int q     = lane >> 4;                   // quarter -> receiver
  const int halfB = wvid >> 1;                   // 0: ell0 cols, 1: ell1 cols

  // ---- prologue ----
  for (int i = tid; i < NN*3; i += 256)
    posL[i] = pos_cur[b*NN*3 + i];
  if (tid < 64) {
    int rr = tid >> 4, j = tid & 15;
    envL[rr][j] = env[(b*NN + r0 + rr)*NN + sbase + j];
    w1L[tid] = cvt[WR1_OFF + layer*64 + tid];
    b1L[tid] = cvt[BR1_OFF + layer*64 + tid];
  }
  bf16x8 bfr[4][2];
  {
    const float* W2 = cvt + WR2_OFF + layer*64*512;
    #pragma unroll
    for (int t = 0; t < 4; ++t) {
      int col = wvid*64 + t*16 + n16;            // 0..255
      #pragma unroll
      for (int ks = 0; ks < 2; ++ks) {
        #pragma unroll
        for (int j = 0; j < 8; ++j) {
          int k = ks*32 + q*8 + j;
          float v = W2[k*512 + col];
          if (halfB) v *= SQRT3_F;
          bfr[t][ks][j] = f2bf(v);
        }
      }
    }
  }
  float acR[12];
  #pragma unroll
  for (int i = 0; i < 12; ++i) acR[i] = 0.f;

  __syncthreads();   // posL/envL/w1L ready

  const int rme = wvid;                          // receiver staged by this wave
  const float hrx = posL[(r0 + rme)*3 + 0];
  const float hry = posL[(r0 + rme)*3 + 1];
  const float hrz = posL[(r0 + rme)*3 + 2];
  const float w1v = w1L[lane], b1v = b1L[lane];

  const int fS  = tid & 127;                     // staging column
  const int si0 = tid >> 7;                      // staging sender base (0/1)

  float4 pv[2];                                  // prefetch registers

  // ---- stage chunk 0 ----
  #pragma unroll
  for (int rep = 0; rep < 2; ++rep) {
    int gs = b*NN + sbase + 0 + si0 + 2*rep;
    pv[rep].x = z[gs*NF + fS];
    if (layer == 0) {
      pv[rep].y = 0.f; pv[rep].z = 0.f; pv[rep].w = 0.f;
    } else {
      pv[rep].y = vec[((size_t)gs*3 + 0)*NF + fS];
      pv[rep].z = vec[((size_t)gs*3 + 1)*NF + fS];
      pv[rep].w = vec[((size_t)gs*3 + 2)*NF + fS];
    }
  }
  #pragma unroll
  for (int si = 0; si < 4; ++si) {
    int s = sbase + si;
    float vx = hrx - posL[s*3 + 0];
    float vy = hry - posL[s*3 + 1];
    float vz = hrz - posL[s*3 + 2];
    float d = vx*vx + vy*vy + vz*vz + 1e-12f;
    float lng = d * fast_rsq(d);
    hidA[0][rme*4 + si][lane] = f2bf(silu_fast(lng * w1v + b1v));
  }
  if (tid < 16) {
    int r = tid >> 2, si = tid & 3;
    int s = sbase + si;
    float vx = posL[(r0 + r)*3 + 0] - posL[s*3 + 0];
    float vy = posL[(r0 + r)*3 + 1] - posL[s*3 + 1];
    float vz = posL[(r0 + r)*3 + 2] - posL[s*3 + 2];
    float d = vx*vx + vy*vy + vz*vz + 1e-12f;
    float inv = fast_rsq(d);
    float envw = (s == r0 + r) ? 0.f : envL[r][si] * 0.0625f;
    uenvL[0][r][si] = make_float4(vx*inv, vy*inv, vz*inv, envw);
  }
  #pragma unroll
  for (int rep = 0; rep < 2; ++rep)
    zvp[0][si0 + 2*rep][fS] = pv[rep];
  __syncthreads();

  // ---- pipelined chunk loop: 1 barrier per chunk ----
  #pragma unroll
  for (int c = 0; c < 4; ++c) {
    const int cb = c & 1, nb = cb ^ 1;
    const int nc0 = (c + 1) * 4;

    // issue next chunk's global loads first (hidden under MFMA)
    if (c < 3) {
      #pragma unroll
      for (int rep = 0; rep < 2; ++rep) {
        int gs = b*NN + sbase + nc0 + si0 + 2*rep;
        pv[rep].x = z[gs*NF + fS];
        if (layer == 0) {
          pv[rep].y = 0.f; pv[rep].z = 0.f; pv[rep].w = 0.f;
        } else {
          pv[rep].y = vec[((size_t)gs*3 + 0)*NF + fS];
          pv[rep].z = vec[((size_t)gs*3 + 1)*NF + fS];
          pv[rep].w = vec[((size_t)gs*3 + 2)*NF + fS];
        }
      }
    }

    // ---- MFMA radial GEMM + consume (buffer cb) ----
    bf16x8 af0 = *(const bf16x8*)&hidA[cb][n16][q*8];
    bf16x8 af1 = *(const bf16x8*)&hidA[cb][n16][q*8 + 32];
    float4 ue[4];
    #pragma unroll
    for (int si = 0; si < 4; ++si) ue[si] = uenvL[cb][q][si];

    #pragma unroll
    for (int t = 0; t < 4; ++t) {
      f32x4 Cf = {0.f, 0.f, 0.f, 0.f};
      Cf = __builtin_amdgcn_mfma_f32_16x16x32_bf16(af0, bfr[t][0], Cf, 0, 0, 0);
      Cf = __builtin_amdgcn_mfma_f32_16x16x32_bf16(af1, bfr[t][1], Cf, 0, 0, 0);
      int f = (wvid*64 + t*16 + n16) & 127;      // feature index
      if (!halfB) {
        float a0 = 0.f;
        #pragma unroll
        for (int si = 0; si < 4; ++si) {
          float4 zv = zvp[cb][si][f];
          float fv = zv.x + ue[si].x*zv.y + ue[si].y*zv.z + ue[si].z*zv.w;
          a0 += (Cf[si] * ue[si].w) * fv;        // C row = q*4+si -> edge(q,si)
        }
        acR[t] += a0;
      } else {
        float t1 = 0.f, t2 = 0.f, t3 = 0.f;
        #pragma unroll
        for (int si = 0; si < 4; ++si) {
          float4 zv = zvp[cb][si][f];
          float fv = zv.x + ue[si].x*zv.y + ue[si].y*zv.z + ue[si].z*zv.w;
          float tt = (Cf[si] * ue[si].w) * fv;   // sqrt3 folded into B
          t1 += tt * ue[si].x;
          t2 += tt * ue[si].y;
          t3 += tt * ue[si].z;
        }
        acR[t*3 + 0] += t1;
        acR[t*3 + 1] += t2;
        acR[t*3 + 2] += t3;
      }
    }

    // ---- stage next chunk into buffer nb ----
    if (c < 3) {
      #pragma unroll
      for (int si = 0; si < 4; ++si) {
        int s = sbase + nc0 + si;
        float vx = hrx - posL[s*3 + 0];
        float vy = hry - posL[s*3 + 1];
        float vz = hrz - posL[s*3 + 2];
        float d = vx*vx + vy*vy + vz*vz + 1e-12f;
        float lng = d * fast_rsq(d);
        hidA[nb][rme*4 + si][lane] = f2bf(silu_fast(lng * w1v + b1v));
      }
      if (tid < 16) {
        int r = tid >> 2, si = tid & 3;
        int s = sbase + nc0 + si;
        float vx = posL[(r0 + r)*3 + 0] - posL[s*3 + 0];
        float vy = posL[(r0 + r)*3 + 1] - posL[s*3 + 1];
        float vz = posL[(r0 + r)*3 + 2] - posL[s*3 + 2];
        float d = vx*vx + vy*vy + vz*vz + 1e-12f;
        float inv = fast_rsq(d);
        float envw = (s == r0 + r) ? 0.f : envL[r][nc0 + si] * 0.0625f;
        uenvL[nb][r][si] = make_float4(vx*inv, vy*inv, vz*inv, envw);
      }
      #pragma unroll
      for (int rep = 0; rep < 2; ++rep)
        zvp[nb][si0 + 2*rep][fS] = pv[rep];
    }
    __syncthreads();
  }

  // ---- epilogue: plain coalesced stores into this sg's private slice ----
  float* slice = Agp + (size_t)sg*AG_SLICE
               + ((size_t)(b*NN + r0 + q)*4)*NF;      // receiver q
  if (!halfB) {
    #pragma unroll
    for (int t = 0; t < 4; ++t) {
      int f = (wvid*64 + t*16 + n16) & 127;
      slice[0*NF + f] = acR[t];
    }
  } else {
    #pragma unroll
    for (int t = 0; t < 4; ++t) {
      int f = (wvid*64 + t*16 + n16) & 127;
      slice[1*NF + f] = acR[t*3 + 0];
      slice[2*NF + f] = acR[t*3 + 1];
      slice[3*NF + f] = acR[t*3 + 2];
    }
  }
}

// ---------------------------------------------------------------------------
// NODE (deterministic): sums the 8 sender-group partial slices in FIXED
// order, then gate, mix GEMMs, z next layer, gate MLP, mbv, pos update.
// No Ag re-zeroing (edge overwrites every element each layer).
// ---------------------------------------------------------------------------
__global__ void node_kernel(const float* __restrict__ Agp,
                            const float* __restrict__ cvt,
                            int layer, int last,
                            float* __restrict__ vec,
                            float* __restrict__ z,
                            float* __restrict__ pos_cur,
                            const int* __restrict__ flag,
                            void* __restrict__ out)
{
  int bn = blockIdx.x;
  int f  = threadIdx.x;   // 0..127
  __shared__ float Ash[4][NF];
  __shared__ float scs[NF];
  __shared__ float h16[16];
  __shared__ float red[2][4];

  {
    float a0 = 0.f, a1 = 0.f, a2 = 0.f, a3 = 0.f;
    #pragma unroll
    for (int sg = 0; sg < 8; ++sg) {             // fixed order -> deterministic
      const float* Ar = Agp + (size_t)sg*AG_SLICE + (size_t)bn*4*NF;
      a0 += Ar[0*NF + f];
      a1 += Ar[1*NF + f];
      a2 += Ar[2*NF + f];
      a3 += Ar[3*NF + f];
    }
    float n0 = a0*a0;
    float C1 = cvt[C1_OFF + (layer*4 + 0)*NF + f];
    float C2 = cvt[C2_OFF + (layer*4 + 0)*NF + f];
    float C3 = cvt[C3_OFF + (layer*4 + 0)*NF + f];
    float g0 = 1.0f + C1*n0 + C2*n0*n0 + C3*n0*n0*n0;
    float n1 = a1*a1 + a2*a2 + a3*a3;
    float D1 = cvt[C1_OFF + (layer*4 + 1)*NF + f];
    float D2 = cvt[C2_OFF + (layer*4 + 1)*NF + f];
    float D3 = cvt[C3_OFF + (layer*4 + 1)*NF + f];
    float g1 = 1.0f + D1*n1 + D2*n1*n1 + D3*n1*n1*n1;
    Ash[0][f] = a0 * g0;
    Ash[1][f] = a1 * g1;
    Ash[2][f] = a2 * g1;
    Ash[3][f] = a3 * g1;
  }
  __syncthreads();

  const float* M0 = cvt + M0_OFF + layer*NF*NF;
  const float* M1 = cvt + M1_OFF + layer*NF*NF;
  float sn = 0.f, v0 = 0.f, v1 = 0.f, v2 = 0.f;
  #pragma unroll 4
  for (int k = 0; k < NF; ++k) {
    float m0 = M0[k*NF + f];
    float m1 = M1[k*NF + f];
    sn += Ash[0][k] * m0;
    v0 += Ash[1][k] * m1;
    v1 += Ash[2][k] * m1;
    v2 += Ash[3][k] * m1;
  }
  scs[f] = sn;
  __syncthreads();

  if (!last) {
    const float* W = cvt + WN_OFF + (layer+1)*NF*NF;
    float acc = 0.f;
    #pragma unroll 8
    for (int k = 0; k < NF; ++k)
      acc += scs[k] * W[k*NF + f];
    z[bn*NF + f] = acc;
  }

  if (f < 16) {
    const float* G1 = cvt + G1_OFF + layer*NF*16;
    float acc = 0.f;
    #pragma unroll 8
    for (int k = 0; k < NF; ++k)
      acc += scs[k] * G1[k*16 + f];
    h16[f] = silu_fast(acc);
  }
  __syncthreads();
  const float* G2 = cvt + G2_OFF + layer*16*NF;
  float gate = 0.f;
  #pragma unroll
  for (int j = 0; j < 16; ++j)
    gate += h16[j] * G2[j*NF + f];
  float gv = gate * cvt[WV_OFF + layer*NF + f];

  if (!last) {
    vec[((size_t)bn*3 + 0)*NF + f] = v0;
    vec[((size_t)bn*3 + 1)*NF + f] = v1;
    vec[((size_t)bn*3 + 2)*NF + f] = v2;
  }

  float p0 = v0*gv, p1 = v1*gv, p2 = v2*gv;
  #pragma unroll
  for (int off = 32; off > 0; off >>= 1) {
    p0 += __shfl_down(p0, off, 64);
    p1 += __shfl_down(p1, off, 64);
    p2 += __shfl_down(p2, off, 64);
  }
  int wave = f >> 6;
  if ((f & 63) == 0) { red[wave][0] = p0; red[wave][1] = p1; red[wave][2] = p2; }
  __syncthreads();
  if (f == 0) {
    float m0 = red[0][0] + red[1][0];
    float m1 = red[0][1] + red[1][1];
    float m2 = red[0][2] + red[1][2];
    float px = pos_cur[bn*3+0] + m0;
    float py = pos_cur[bn*3+1] + m1;
    float pz = pos_cur[bn*3+2] + m2;
    pos_cur[bn*3+0] = px;
    pos_cur[bn*3+1] = py;
    pos_cur[bn*3+2] = pz;
    if (last) {
      float ox = px - cvt[POS_OFF + bn*3+0];
      float oy = py - cvt[POS_OFF + bn*3+1];
      float oz = pz - cvt[POS_OFF + bn*3+2];
      if (*flag) {
        bf16* o = (bf16*)out;
        o[bn*3+0] = __float2bfloat16(ox);
        o[bn*3+1] = __float2bfloat16(oy);
        o[bn*3+2] = __float2bfloat16(oz);
      } else {
        float* o = (float*)out;
        o[bn*3+0] = ox;
        o[bn*3+1] = oy;
        o[bn*3+2] = oz;
      }
    }
  }
}

// ---------------------------------------------------------------------------
extern "C" void kernel_launch(void* const* d_in, const int* in_sizes, int n_in,
                              void* d_out, int out_size, void* d_ws, size_t ws_size,
                              hipStream_t stream)
{
  (void)in_sizes; (void)n_in; (void)out_size; (void)ws_size;
  const int* nfeat = (const int*)d_in[1];

  float* ws      = (float*)d_ws;
  int*   flag    = (int*)ws;                  // 16 floats reserved
  float* cvt     = ws + 16;                   // CVT_TOTAL floats
  float* pos_cur = cvt + CVT_TOTAL;           // 1536
  float* z       = pos_cur + NB*NN*3;         // 65536
  float* vec     = z + NB*NN*NF;              // 196608
  float* env     = vec + NB*NN*3*NF;          // 65536
  float* Agp     = env + NB*NN*NN;            // 8 * 262144 floats (8.4 MB)

  prep_convert_kernel<<<512, 256, 0, stream>>>(
      d_in[0], nfeat, d_in[2], d_in[3], d_in[4], d_in[5], d_in[6], d_in[7],
      d_in[8], d_in[9], d_in[10], d_in[11], d_in[12], d_in[13], d_in[14],
      d_in[15], d_in[16], flag, cvt, pos_cur, z, env);
  for (int i = 0; i < NL; ++i) {
    edge_kernel<<<1024, 256, 0, stream>>>(pos_cur, z, vec, env, cvt, i, Agp);
    node_kernel<<<NB*NN, NF, 0, stream>>>(Agp, cvt, i, (i == NL-1) ? 1 : 0,
                                          vec, z, pos_cur, flag, d_out);
  }
}